// Round 8
// baseline (93.794 us; speedup 1.0000x reference)
//
#include <hip/hip_runtime.h>
#include <cstddef>

#define NCAPS  10
#define BATCH  256
#define NROUTE 1152
#define CIN    8
#define COUT   16
#define T      512           // 8 waves; LDS ~37.6KB -> 4 blocks/CU = 32 waves/CU
#define NWAVE  (T / 64)
#define NBLK   (NCAPS * BATCH)          // 2560 blocks = exactly 10 rounds/CU
#define PLANE  (NROUTE * 8)             // u32 (bf16x2) per plane = 9216
#define XPLANE (NROUTE * CIN)           // floats per x b-plane = 9216

// bijective 16B-unit swizzle (validated rounds 5-7): conflict-minimal ds_read
__device__ __forceinline__ unsigned swzu(unsigned unit) { return unit ^ ((unit >> 3) & 3u); }

// pack two fp32 -> bf16x2 (RNE), low16 = a
__device__ __forceinline__ unsigned pack_bf16(float a, float b) {
    unsigned ua = __float_as_uint(a); ua += 0x7fffu + ((ua >> 16) & 1u);
    unsigned ub = __float_as_uint(b); ub += 0x7fffu + ((ub >> 16) & 1u);
    return (ua >> 16) | (ub & 0xffff0000u);
}
__device__ __forceinline__ float blo(unsigned u) { return __uint_as_float(u << 16); }
__device__ __forceinline__ float bhi(unsigned u) { return __uint_as_float(u & 0xffff0000u); }

__device__ __forceinline__ float wave_sum(float v) {
    v += __shfl_xor(v, 1);  v += __shfl_xor(v, 2);  v += __shfl_xor(v, 4);
    v += __shfl_xor(v, 8);  v += __shfl_xor(v, 16); v += __shfl_xor(v, 32);
    return v;
}

// Component-splitting butterfly: reduces s[0..15] over 64 lanes. Lane L (L<16)
// ends with the wave total of comp(L)=((L&1)<<3)|((L&2)<<1)|((L&4)>>1)|((L&8)>>3).
__device__ __forceinline__ float wave_sum16(float* s, int lane) {
#pragma unroll
    for (int j = 0; j < 8; ++j) {
        float snd = (lane & 1) ? s[j] : s[j + 8];
        float r = __shfl_xor(snd, 1);
        s[j] = ((lane & 1) ? s[j + 8] : s[j]) + r;
    }
#pragma unroll
    for (int j = 0; j < 4; ++j) {
        float snd = (lane & 2) ? s[j] : s[j + 4];
        float r = __shfl_xor(snd, 2);
        s[j] = ((lane & 2) ? s[j + 4] : s[j]) + r;
    }
#pragma unroll
    for (int j = 0; j < 2; ++j) {
        float snd = (lane & 4) ? s[j] : s[j + 2];
        float r = __shfl_xor(snd, 4);
        s[j] = ((lane & 4) ? s[j + 2] : s[j]) + r;
    }
    {
        float snd = (lane & 8) ? s[0] : s[1];
        float r = __shfl_xor(snd, 8);
        s[0] = ((lane & 8) ? s[1] : s[0]) + r;
    }
    s[0] += __shfl_xor(s[0], 16);
    s[0] += __shfl_xor(s[0], 32);
    return s[0];
}

union U4 { uint4 v; unsigned u[4]; };
union U2 { uint2 v; unsigned u[2]; };

__global__ __launch_bounds__(T) void caps_routing(const float* __restrict__ x,
                                                  const float* __restrict__ W,
                                                  float* __restrict__ out) {
    __shared__ unsigned prLDS[PLANE];               // 36864 B: priors bf16x2, swizzled
    __shared__ float sred[NWAVE][20];               // [wave][comp 0..15, 16=sumExp]
    __shared__ __align__(16) float VLDS[COUT];      // cumulative output (= logit state)

    const int tid  = threadIdx.x;
    const int lane = tid & 63;
    const int wv   = tid >> 6;

    // XCD-aware swizzle: contiguous widx per XCD -> <=2 capsules -> W (<=1.18MB)
    // stays L2-resident per XCD.
    int g    = blockIdx.x;
    int widx = (g & 7) * (NBLK / 8) + (g >> 3);   // bijective, 2560 % 8 == 0
    int c    = widx >> 8;                          // / BATCH-per-c = 256
    int b0   = widx & 255;

    const float* Wc = W + (size_t)c * (NROUTE * CIN * COUT);
    const float* xb = x + (size_t)b0 * XPLANE;

    // ---------------- Phase A: (route, out-quad) per thread, 9 passes -------
    // ~30 live VGPR; W read once per block as coalesced float4.
#pragma unroll 3
    for (int pass = 0; pass < (NROUTE * 4) / T; ++pass) {
        const int r  = pass * (T / 4) + (tid >> 2);
        const int j4 = tid & 3;                       // out-quad: outs 4*j4..4*j4+3
        const float4* xq = (const float4*)(xb + r * CIN);
        float4 xa = xq[0], xv = xq[1];                // 4-lane broadcast
        float xs[CIN] = {xa.x, xa.y, xa.z, xa.w, xv.x, xv.y, xv.z, xv.w};
        float4 acc = {0.f, 0.f, 0.f, 0.f};
        const float* wq = Wc + (size_t)r * (CIN * COUT) + j4 * 4;
#pragma unroll
        for (int i = 0; i < CIN; ++i) {
            float4 w = *(const float4*)(wq + i * COUT);
            acc.x = fmaf(xs[i], w.x, acc.x);
            acc.y = fmaf(xs[i], w.y, acc.y);
            acc.z = fmaf(xs[i], w.z, acc.z);
            acc.w = fmaf(xs[i], w.w, acc.w);
        }
        U2 q;
        q.u[0] = pack_bf16(acc.x, acc.y);
        q.u[1] = pack_bf16(acc.z, acc.w);
        // quad j4: lives in unit 2r+(j4>>1), u32 offset (j4&1)*2 (8B-aligned)
        const unsigned base = swzu(2u * (unsigned)r + (unsigned)(j4 >> 1)) * 4u + (unsigned)(j4 & 1) * 2u;
        *(uint2*)&prLDS[base] = q.v;
    }
    __syncthreads();

    // ---------------- Phase B: 3 routing iterations -------------------------
    // Linearity: logit_r = p_r . V where V = cumulative sum of previous outputs.
    const int r2 = 1024 + (tid >> 2);   // leftover route (4 threads/route)
    const int j2 = tid & 3;             // out-quad within r2
    const int comp = ((lane & 1) << 3) | ((lane & 2) << 1) | ((lane & 4) >> 1) | ((lane & 8) >> 3);

#pragma unroll 1
    for (int it = 0; it < 3; ++it) {
        float s16[COUT];
        float se = 0.f;
#pragma unroll
        for (int o = 0; o < COUT; ++o) s16[o] = 0.f;

        // 2 main routes (independent bodies -> ILP)
#pragma unroll
        for (int k = 0; k < 2; ++k) {
            const int r = (k << 9) + tid;
            const unsigned d0 = swzu(2u * (unsigned)r) * 4u;
            const unsigned d1 = swzu(2u * (unsigned)r + 1u) * 4u;
            U4 qa, qb;
            qa.v = *(const uint4*)&prLDS[d0];
            qb.v = *(const uint4*)&prLDS[d1];
            float p[COUT];
#pragma unroll
            for (int q = 0; q < 4; ++q) {
                p[2 * q]     = blo(qa.u[q]);  p[2 * q + 1] = bhi(qa.u[q]);
                p[8 + 2 * q] = blo(qb.u[q]);  p[9 + 2 * q] = bhi(qb.u[q]);
            }
            float e;
            if (it > 0) {
                float d = 0.f;
#pragma unroll
                for (int q = 0; q < 4; ++q) {
                    float4 v4 = *(const float4*)&VLDS[4 * q];   // broadcast read
                    d = fmaf(p[4 * q + 0], v4.x, d);
                    d = fmaf(p[4 * q + 1], v4.y, d);
                    d = fmaf(p[4 * q + 2], v4.z, d);
                    d = fmaf(p[4 * q + 3], v4.w, d);
                }
                e = __expf(d);   // logit bounded ~|45|, fp32 exp safe
            } else {
                e = 1.f;
            }
            se += e;
#pragma unroll
            for (int o = 0; o < COUT; ++o) s16[o] = fmaf(e, p[o], s16[o]);
        }

        // leftover route: out-quad per thread, 4 lanes cooperate per route
        {
            const unsigned dw = swzu(2u * (unsigned)r2 + (unsigned)(j2 >> 1)) * 4u + (unsigned)(j2 & 1) * 2u;
            U2 q;
            q.v = *(const uint2*)&prLDS[dw];
            float pl[4] = {blo(q.u[0]), bhi(q.u[0]), blo(q.u[1]), bhi(q.u[1])};
            float e2;
            if (it > 0) {
                float d2 = 0.f;
#pragma unroll
                for (int j = 0; j < 4; ++j) d2 = fmaf(pl[j], VLDS[4 * j2 + j], d2);
                d2 += __shfl_xor(d2, 1);    // combine quads (lanes of same route
                d2 += __shfl_xor(d2, 2);    // group are adjacent: tid>>2 shared)
                e2 = __expf(d2);
            } else {
                e2 = 1.f;
            }
            se += 0.25f * e2;               // 4 lanes each add 1/4 of exp -> exact
#pragma unroll
            for (int o = 0; o < COUT; ++o) {
                const float add = e2 * pl[o & 3];
                s16[o] += ((o >> 2) == j2) ? add : 0.f;   // predicated
            }
        }

        const float sv  = wave_sum16(s16, lane);
        const float sev = wave_sum(se);
        if (lane < 16) sred[wv][comp] = sv;
        if (lane == 0) sred[wv][16]   = sev;
        __syncthreads();

        if (tid < COUT) {          // 16 threads: reduce 8 waves + squash
            const int o = tid;
            float S = 0.f, SE = 0.f;
#pragma unroll
            for (int w = 0; w < NWAVE; ++w) {
                S  += sred[w][o];
                SE += sred[w][16];
            }
            const float tt = S / SE;
            float pq = tt * tt;
            pq += __shfl_xor(pq, 1); pq += __shfl_xor(pq, 2);
            pq += __shfl_xor(pq, 4); pq += __shfl_xor(pq, 8);   // |s|^2 over 16 lanes
            const float scale = pq / ((1.f + pq) * sqrtf(pq));
            const float val = tt * scale;
            if (it == 2) {
                out[((size_t)c * BATCH + b0) * COUT + o] = val;
            } else {
                VLDS[o] = (it == 0) ? val : (VLDS[o] + val);    // cumulative V
            }
        }
        __syncthreads();
    }
}

extern "C" void kernel_launch(void* const* d_in, const int* in_sizes, int n_in,
                              void* d_out, int out_size, void* d_ws, size_t ws_size,
                              hipStream_t stream) {
    const float* x = (const float*)d_in[0];
    const float* w = (const float*)d_in[1];
    float* out = (float*)d_out;
    hipLaunchKernelGGL(caps_routing, dim3(NBLK), dim3(T), 0, stream, x, w, out);
}

// Round 10
// 75.833 us; speedup vs baseline: 1.2369x; 1.2369x over previous
//
#include <hip/hip_runtime.h>
#include <cstddef>

#define NCAPS  10
#define BATCH  256
#define NROUTE 1152
#define CIN    8
#define COUT   16
#define T      1024          // 16 waves; LDS ~75KB -> 2 blocks/CU = 32 waves/CU
#define NB     2             // batch elements per block (W economy: 755MB total)
#define NWAVE  (T / 64)
#define NBLK   (NCAPS * (BATCH / NB))   // 1280 blocks
#define PLANE  (NROUTE * 8)             // u32 (bf16x2) per b-plane = 9216
#define XPLANE (NROUTE * CIN)           // floats per x b-plane = 9216

// bijective 16B-unit swizzle (validated rounds 5-8): conflict-minimal ds_read
__device__ __forceinline__ unsigned swzu(unsigned unit) { return unit ^ ((unit >> 3) & 3u); }

// pack two fp32 -> bf16x2 (RNE), low16 = a
__device__ __forceinline__ unsigned pack_bf16(float a, float b) {
    unsigned ua = __float_as_uint(a); ua += 0x7fffu + ((ua >> 16) & 1u);
    unsigned ub = __float_as_uint(b); ub += 0x7fffu + ((ub >> 16) & 1u);
    return (ua >> 16) | (ub & 0xffff0000u);
}
__device__ __forceinline__ float blo(unsigned u) { return __uint_as_float(u << 16); }
__device__ __forceinline__ float bhi(unsigned u) { return __uint_as_float(u & 0xffff0000u); }

__device__ __forceinline__ float wave_sum(float v) {
    v += __shfl_xor(v, 1);  v += __shfl_xor(v, 2);  v += __shfl_xor(v, 4);
    v += __shfl_xor(v, 8);  v += __shfl_xor(v, 16); v += __shfl_xor(v, 32);
    return v;
}

// Component-splitting butterfly: reduces s[0..15] over 64 lanes. Lane L (L<16)
// ends with the wave total of comp(L)=((L&1)<<3)|((L&2)<<1)|((L&4)>>1)|((L&8)>>3).
__device__ __forceinline__ float wave_sum16(float* s, int lane) {
#pragma unroll
    for (int j = 0; j < 8; ++j) {
        float snd = (lane & 1) ? s[j] : s[j + 8];
        float r = __shfl_xor(snd, 1);
        s[j] = ((lane & 1) ? s[j + 8] : s[j]) + r;
    }
#pragma unroll
    for (int j = 0; j < 4; ++j) {
        float snd = (lane & 2) ? s[j] : s[j + 4];
        float r = __shfl_xor(snd, 2);
        s[j] = ((lane & 2) ? s[j + 4] : s[j]) + r;
    }
#pragma unroll
    for (int j = 0; j < 2; ++j) {
        float snd = (lane & 4) ? s[j] : s[j + 2];
        float r = __shfl_xor(snd, 4);
        s[j] = ((lane & 4) ? s[j + 2] : s[j]) + r;
    }
    {
        float snd = (lane & 8) ? s[0] : s[1];
        float r = __shfl_xor(snd, 8);
        s[0] = ((lane & 8) ? s[1] : s[0]) + r;
    }
    s[0] += __shfl_xor(s[0], 16);
    s[0] += __shfl_xor(s[0], 32);
    return s[0];
}

union U4 { uint4 v; unsigned u[4]; };
union U2 { uint2 v; unsigned u[2]; };

// Phase-A unit: route r=u>>2, out-quad j4=u&3 (outs 4*j4..4*j4+3).
// float4 W loads; each W row serves NB=2 batch elements. ~45 live VGPR.
__device__ __forceinline__ void phaseA_unit(int u, const float* __restrict__ Wc,
                                            const float* __restrict__ xb,
                                            unsigned* prLDS) {
    const int r  = u >> 2;
    const int j4 = u & 3;
    float xs[NB][CIN];
#pragma unroll
    for (int b = 0; b < NB; ++b) {
        const float4* xq = (const float4*)(xb + (size_t)b * XPLANE + r * CIN);
        float4 xa = xq[0], xv = xq[1];
        xs[b][0] = xa.x; xs[b][1] = xa.y; xs[b][2] = xa.z; xs[b][3] = xa.w;
        xs[b][4] = xv.x; xs[b][5] = xv.y; xs[b][6] = xv.z; xs[b][7] = xv.w;
    }
    float4 acc[NB];
#pragma unroll
    for (int b = 0; b < NB; ++b) acc[b] = make_float4(0.f, 0.f, 0.f, 0.f);
    const float* wq = Wc + (size_t)r * (CIN * COUT) + j4 * 4;
#pragma unroll
    for (int i = 0; i < CIN; ++i) {
        float4 w = *(const float4*)(wq + i * COUT);
#pragma unroll
        for (int b = 0; b < NB; ++b) {
            acc[b].x = fmaf(xs[b][i], w.x, acc[b].x);
            acc[b].y = fmaf(xs[b][i], w.y, acc[b].y);
            acc[b].z = fmaf(xs[b][i], w.z, acc[b].z);
            acc[b].w = fmaf(xs[b][i], w.w, acc[b].w);
        }
    }
    const unsigned base = swzu(2u * (unsigned)r + (unsigned)(j4 >> 1)) * 4u
                        + (unsigned)(j4 & 1) * 2u;
#pragma unroll
    for (int b = 0; b < NB; ++b) {
        U2 q;
        q.u[0] = pack_bf16(acc[b].x, acc[b].y);
        q.u[1] = pack_bf16(acc[b].z, acc[b].w);
        *(uint2*)&prLDS[b * PLANE + base] = q.v;
    }
}

__global__ __launch_bounds__(T) void caps_routing(const float* __restrict__ x,
                                                  const float* __restrict__ W,
                                                  float* __restrict__ out) {
    __shared__ unsigned prLDS[NB * PLANE];          // 73728 B: priors bf16x2, swizzled
    __shared__ float sred[NWAVE][20];               // [wave][comp 0..15, 16=sumExp]
    __shared__ __align__(16) float VLDS[NB][COUT];  // cumulative output (= logit state)

    const int tid  = threadIdx.x;
    const int lane = tid & 63;
    const int wv   = tid >> 6;

    // XCD-aware swizzle: contiguous widx per XCD -> <=2 capsules -> W (<=1.18MB)
    // stays L2-resident per XCD.
    int g    = blockIdx.x;
    int widx = (g & 7) * (NBLK / 8) + (g >> 3);   // bijective, 1280 % 8 == 0
    int c    = widx >> 7;                          // / (BATCH/NB = 128)
    int b0   = (widx & 127) * NB;

    const float* Wc = W + (size_t)c * (NROUTE * CIN * COUT);
    const float* xb = x + (size_t)b0 * XPLANE;

    // ---------------- Phase A: 4608 units = 4*1024 + 512 --------------------
#pragma unroll 1
    for (int pass = 0; pass < 4; ++pass) {
        phaseA_unit(pass * T + tid, Wc, xb, prLDS);
    }
    if (tid < 512) {                     // half-pass: waves 0-7
        phaseA_unit(4 * T + tid, Wc, xb, prLDS);
    }
    __syncthreads();

    // ---------------- Phase B: b-split, 3 routing iterations ----------------
    // Thread owns b = tid>>9; 512 threads per b: 2 main routes + leftover quad.
    // Linearity: logit_r = p_r . V, V = cumulative sum of previous outputs.
    const int bb = tid >> 9;            // waves 0-7 -> b=0, 8-15 -> b=1
    const int tl = tid & 511;
    const int r2 = 1024 + (tl >> 2);    // leftover route (4 threads/route)
    const int j2 = tl & 3;              // out-quad within r2
    const int comp = ((lane & 1) << 3) | ((lane & 2) << 1) | ((lane & 4) >> 1) | ((lane & 8) >> 3);

#pragma unroll 1
    for (int it = 0; it < 3; ++it) {
        float s16[COUT];
        float se = 0.f;
#pragma unroll
        for (int o = 0; o < COUT; ++o) s16[o] = 0.f;

        // 2 main routes (independent bodies -> ILP)
#pragma unroll
        for (int k = 0; k < 2; ++k) {
            const int r = (k << 9) + tl;
            const unsigned d0 = bb * PLANE + swzu(2u * (unsigned)r) * 4u;
            const unsigned d1 = bb * PLANE + swzu(2u * (unsigned)r + 1u) * 4u;
            U4 qa, qb;
            qa.v = *(const uint4*)&prLDS[d0];
            qb.v = *(const uint4*)&prLDS[d1];
            float p[COUT];
#pragma unroll
            for (int q = 0; q < 4; ++q) {
                p[2 * q]     = blo(qa.u[q]);  p[2 * q + 1] = bhi(qa.u[q]);
                p[8 + 2 * q] = blo(qb.u[q]);  p[9 + 2 * q] = bhi(qb.u[q]);
            }
            float e;
            if (it > 0) {
                float d = 0.f;
#pragma unroll
                for (int q = 0; q < 4; ++q) {
                    float4 v4 = *(const float4*)&VLDS[bb][4 * q];   // broadcast read
                    d = fmaf(p[4 * q + 0], v4.x, d);
                    d = fmaf(p[4 * q + 1], v4.y, d);
                    d = fmaf(p[4 * q + 2], v4.z, d);
                    d = fmaf(p[4 * q + 3], v4.w, d);
                }
                e = __expf(d);   // logit bounded ~|45|, fp32 exp safe
            } else {
                e = 1.f;
            }
            se += e;
#pragma unroll
            for (int o = 0; o < COUT; ++o) s16[o] = fmaf(e, p[o], s16[o]);
        }

        // leftover route: out-quad per thread, 4 adjacent lanes cooperate
        {
            const unsigned dw = bb * PLANE + swzu(2u * (unsigned)r2 + (unsigned)(j2 >> 1)) * 4u
                              + (unsigned)(j2 & 1) * 2u;
            U2 q;
            q.v = *(const uint2*)&prLDS[dw];
            float pl[4] = {blo(q.u[0]), bhi(q.u[0]), blo(q.u[1]), bhi(q.u[1])};
            float e2;
            if (it > 0) {
                float d2 = 0.f;
#pragma unroll
                for (int j = 0; j < 4; ++j) d2 = fmaf(pl[j], VLDS[bb][4 * j2 + j], d2);
                d2 += __shfl_xor(d2, 1);    // combine the 4 quads (adjacent lanes)
                d2 += __shfl_xor(d2, 2);
                e2 = __expf(d2);
            } else {
                e2 = 1.f;
            }
            se += 0.25f * e2;               // 4 lanes each add 1/4 of exp -> exact
#pragma unroll
            for (int o = 0; o < COUT; ++o) {
                const float add = e2 * pl[o & 3];
                s16[o] += ((o >> 2) == j2) ? add : 0.f;   // predicated
            }
        }

        const float sv  = wave_sum16(s16, lane);
        const float sev = wave_sum(se);
        if (lane < 16) sred[wv][comp] = sv;
        if (lane == 0) sred[wv][16]   = sev;
        __syncthreads();

        if (tid < NB * COUT) {          // 32 threads: reduce 8 waves/b + squash
            const int b = tid >> 4, o = tid & 15;
            float S = 0.f, SE = 0.f;
#pragma unroll
            for (int w = 0; w < 8; ++w) {
                S  += sred[b * 8 + w][o];
                SE += sred[b * 8 + w][16];
            }
            const float tt = S / SE;
            float pq = tt * tt;
            pq += __shfl_xor(pq, 1); pq += __shfl_xor(pq, 2);
            pq += __shfl_xor(pq, 4); pq += __shfl_xor(pq, 8);   // |s|^2 per 16-group
            const float scale = pq / ((1.f + pq) * sqrtf(pq));
            const float val = tt * scale;
            if (it == 2) {
                out[((size_t)c * BATCH + b0 + b) * COUT + o] = val;
            } else {
                VLDS[b][o] = (it == 0) ? val : (VLDS[b][o] + val);  // cumulative V
            }
        }
        __syncthreads();
    }
}

extern "C" void kernel_launch(void* const* d_in, const int* in_sizes, int n_in,
                              void* d_out, int out_size, void* d_ws, size_t ws_size,
                              hipStream_t stream) {
    const float* x = (const float*)d_in[0];
    const float* w = (const float*)d_in[1];
    float* out = (float*)d_out;
    hipLaunchKernelGGL(caps_routing, dim3(NBLK), dim3(T), 0, stream, x, w, out);
}